// Round 2
// baseline (354.570 us; speedup 1.0000x reference)
//
#include <hip/hip_runtime.h>

#define NZ 81          // 9x9 zones
#define OBS_DIM 48
#define MAX_ADJ 5
#define NEG_INF -1000000000.0f
#define BLOCK 256

__global__ __launch_bounds__(BLOCK) void taxi_actor_kernel(
    const float* __restrict__ obs,   // [B, 48]
    const float* __restrict__ W,     // [81, 48, 5]
    const float* __restrict__ bias,  // [81, 5]
    const int*   __restrict__ idx,   // [81, 5]
    const float* __restrict__ mask,  // [81, 5]
    float* __restrict__ out)         // [B, 81, 81]
{
    __shared__ float s_obs[OBS_DIM];
    __shared__ float s_out[NZ * NZ];   // 6561 floats = 26244 B

    const int b   = blockIdx.x;
    const int tid = threadIdx.x;

    // Load this batch row's observation into LDS.
    if (tid < OBS_DIM) s_obs[tid] = obs[(size_t)b * OBS_DIM + tid];

    // Zero the 81x81 output tile in LDS.
    for (int i = tid; i < NZ * NZ; i += BLOCK) s_out[i] = 0.0f;
    __syncthreads();

    // 81 threads: one zone each. 5 dot-48 products + masked softmax + scatter.
    if (tid < NZ) {
        const int n = tid;
        float logits[MAX_ADJ];
        #pragma unroll
        for (int k = 0; k < MAX_ADJ; ++k) logits[k] = bias[n * MAX_ADJ + k];

        const float* __restrict__ Wn = W + (size_t)n * OBS_DIM * MAX_ADJ;
        #pragma unroll 4
        for (int d = 0; d < OBS_DIM; ++d) {
            const float x = s_obs[d];
            #pragma unroll
            for (int k = 0; k < MAX_ADJ; ++k)
                logits[k] = fmaf(x, Wn[d * MAX_ADJ + k], logits[k]);
        }

        float mk[MAX_ADJ];
        float m = NEG_INF;
        #pragma unroll
        for (int k = 0; k < MAX_ADJ; ++k) {
            mk[k] = mask[n * MAX_ADJ + k];
            logits[k] = (mk[k] > 0.0f) ? logits[k] : NEG_INF;
            m = fmaxf(m, logits[k]);
        }
        float p[MAX_ADJ];
        float s = 0.0f;
        #pragma unroll
        for (int k = 0; k < MAX_ADJ; ++k) {
            p[k] = expf(logits[k] - m);   // masked -> exp(-1e9) == 0.0f
            s += p[k];
        }
        const float inv = 1.0f / s;
        #pragma unroll
        for (int k = 0; k < MAX_ADJ; ++k) {
            if (mk[k] > 0.0f) {
                const int z = idx[n * MAX_ADJ + k];   // distinct z per k within row n
                s_out[n * NZ + z] = p[k] * inv;
            }
        }
    }
    __syncthreads();

    // Coalesced streaming store of the tile.
    float* __restrict__ outb = out + (size_t)b * (NZ * NZ);
    for (int i = tid; i < NZ * NZ; i += BLOCK) outb[i] = s_out[i];
}

extern "C" void kernel_launch(void* const* d_in, const int* in_sizes, int n_in,
                              void* d_out, int out_size, void* d_ws, size_t ws_size,
                              hipStream_t stream) {
    const float* obs  = (const float*)d_in[0];
    const float* W    = (const float*)d_in[1];
    const float* bias = (const float*)d_in[2];
    const int*   idx  = (const int*)d_in[3];
    const float* mask = (const float*)d_in[4];
    float* out = (float*)d_out;

    const int B = in_sizes[0] / OBS_DIM;   // 32768

    taxi_actor_kernel<<<B, BLOCK, 0, stream>>>(obs, W, bias, idx, mask, out);
}